// Round 1
// baseline (180.076 us; speedup 1.0000x reference)
//
#include <hip/hip_runtime.h>
#include <hip/hip_bf16.h>
#include <stdint.h>

// Problem constants
#define BS   8
#define CIN  256
#define COUT 256
#define SD   512
#define HH   64
#define WW   64
#define HP   66   // padded spatial dim

typedef __attribute__((ext_vector_type(8))) short short8;
typedef __attribute__((ext_vector_type(4))) float f32x4;

__device__ __forceinline__ unsigned short f2bf(float f) {
    __hip_bfloat16 h = __float2bfloat16(f);
    return *reinterpret_cast<unsigned short*>(&h);
}

typedef __attribute__((address_space(3))) unsigned int lds_u32_t;
typedef const __attribute__((address_space(1))) unsigned int glb_u32_t;

__device__ __forceinline__ void async16(const void* g, void* l) {
    __builtin_amdgcn_global_load_lds((glb_u32_t*)g, (lds_u32_t*)l, 16, 0, 0);
}

// ---------------------------------------------------------------------------
// K1: style[b,i] = s[b,:] . affine_w[i,:] + affine_b[i];  m = style + 1
// grid: BS blocks x 256 threads
__global__ void k_style(const float* __restrict__ s, const float* __restrict__ aw,
                        const float* __restrict__ ab, float* __restrict__ m) {
    int b = blockIdx.x;
    int i = threadIdx.x;
    __shared__ float sv[SD];
    for (int d = threadIdx.x; d < SD; d += 256) sv[d] = s[b * SD + d];
    __syncthreads();
    const float4* awr = (const float4*)(aw + (size_t)i * SD);
    float acc = 0.f;
#pragma unroll 4
    for (int d4 = 0; d4 < SD / 4; ++d4) {
        float4 w4 = awr[d4];
        acc += w4.x * sv[d4 * 4] + w4.y * sv[d4 * 4 + 1] +
               w4.z * sv[d4 * 4 + 2] + w4.w * sv[d4 * 4 + 3];
    }
    m[b * CIN + i] = acc + ab[i] + 1.0f;
}

// ---------------------------------------------------------------------------
// K2: repack w -> wb[t][o][i] (bf16 bits), and wsq[o][i] = sum_t w^2
// grid: COUT blocks x CIN threads
__global__ void k_wprep(const float* __restrict__ w, unsigned short* __restrict__ wb,
                        float* __restrict__ wsq) {
    int o = blockIdx.x, i = threadIdx.x;
    const float* wp = w + ((size_t)o * CIN + i) * 9;
    float v[9];
    float q = 0.f;
#pragma unroll
    for (int t = 0; t < 9; ++t) { v[t] = wp[t]; q += v[t] * v[t]; }
    wsq[o * CIN + i] = q;
#pragma unroll
    for (int t = 0; t < 9; ++t)
        wb[((size_t)t * COUT + o) * CIN + i] = f2bf(v[t]);
}

// ---------------------------------------------------------------------------
// K3: dinv[b,o] = rsqrt( sum_i m[b,i]^2 * wsq[o,i] + 1e-8 )
// grid: BS blocks x COUT threads
__global__ void k_dinv(const float* __restrict__ m, const float* __restrict__ wsq,
                       float* __restrict__ dinv) {
    int b = blockIdx.x, o = threadIdx.x;
    __shared__ float m2[CIN];
    float mv = m[b * CIN + o];
    m2[o] = mv * mv;
    __syncthreads();
    const float4* wq = (const float4*)(wsq + (size_t)o * CIN);
    float acc = 0.f;
#pragma unroll 4
    for (int i4 = 0; i4 < CIN / 4; ++i4) {
        float4 q = wq[i4];
        acc += q.x * m2[i4 * 4] + q.y * m2[i4 * 4 + 1] +
               q.z * m2[i4 * 4 + 2] + q.w * m2[i4 * 4 + 3];
    }
    dinv[b * COUT + o] = rsqrtf(acc + 1e-8f);
}

// ---------------------------------------------------------------------------
// K4: x' = x * m, NCHW fp32 -> zero-padded NHWC bf16 [BS][66][66][CIN]
// grid: BS*HP blocks x 256 threads; block = one padded output row (b, yp)
__global__ void k_xprep(const float* __restrict__ x, const float* __restrict__ m,
                        unsigned short* __restrict__ xp) {
    int bi = blockIdx.x;
    int b = bi / HP, yp = bi % HP;
    unsigned short* row = xp + ((size_t)(b * HP + yp)) * HP * CIN;
    int tid = threadIdx.x;

    if (yp == 0 || yp == HP - 1) {
        uint32_t* r32 = (uint32_t*)row;
        for (int j = tid; j < HP * CIN / 2; j += 256) r32[j] = 0u;
        return;
    }
    int y = yp - 1;
    int lane = tid & 63, wid = tid >> 6;
    __shared__ unsigned short sbuf[CIN][WW + 2];  // +2 pad: conflict-free transpose

    for (int c = 0; c < 64; ++c) {
        int i = c * 4 + wid;
        float v = x[(((size_t)b * CIN + i) * HH + y) * WW + lane];
        float mv = m[b * CIN + i];
        sbuf[i][lane] = f2bf(v * mv);
    }
    __syncthreads();

    // interior columns xp=1..64: channels contiguous -> coalesced writes
    for (int xi = 0; xi < WW; ++xi) {
        row[(xi + 1) * CIN + tid] = sbuf[tid][xi];
    }
    // border columns xp=0 and xp=65
    row[tid] = 0;
    row[(HP - 1) * CIN + tid] = 0;
}

// ---------------------------------------------------------------------------
// K5: implicit GEMM conv. M = BS*HH*WW (b,y,x), N = COUT, K = 9 taps x CIN.
// 128x128 tile, BK=32, 4 waves each 64x64 via 4x4 frags of 16x16x32 bf16 MFMA.
// A staged from padded NHWC x' (no boundary predication needed).
// Epilogue: *dinv[b,o] + bias[o], float4 stores to NCHW output.
__global__ void k_conv(const unsigned short* __restrict__ xp,
                       const unsigned short* __restrict__ wb,
                       const float* __restrict__ dinv,
                       const float* __restrict__ bias,
                       float* __restrict__ out) {
    __shared__ unsigned short As[128 * 32];
    __shared__ unsigned short Bs[128 * 32];

    int bx = blockIdx.x;
    int n0 = (bx & 1) * 128;      // 2 N-tiles
    int mt = bx >> 1;             // 256 M-tiles
    int m0 = mt * 128;
    int b  = m0 >> 12;            // 4096 spatial positions per sample
    int y0 = (m0 >> 6) & 63;      // tile covers image rows y0, y0+1

    int tid = threadIdx.x;
    int lane = tid & 63, wid = tid >> 6;
    int wm = (wid & 1) * 64, wn = (wid >> 1) * 64;

    f32x4 acc[4][4] = {};

    // staging indices: thread covers 16B = 8 channels
    int r  = tid >> 2;            // row within half-tile: 0..63
    int cb = (tid & 3) * 8;       // channel sub-offset (elements)

    const unsigned short* xb = xp + (size_t)b * HP * HP * CIN;

    int ks = (lane >> 4) * 8;     // frag K offset
    int rA = wm + (lane & 15);
    int rB = wn + (lane & 15);

#pragma unroll 1
    for (int t = 0; t < 9; ++t) {
        int dy = t / 3, dx = t % 3;
        // A row r (x = r) maps to x'[b][y0 + (r>>6) + dy][r&63 + dx][ch]
        const unsigned short* a0 = xb + ((size_t)(y0 + dy) * HP + dx) * CIN;
        const unsigned short* a1 = xb + ((size_t)(y0 + 1 + dy) * HP + dx) * CIN;
        const unsigned short* bp = wb + ((size_t)t * COUT + n0) * CIN;

#pragma unroll 1
        for (int kc = 0; kc < 8; ++kc) {
            int ko = kc * 32 + cb;
            // stage A (128 x 32) and B (128 x 32) via async global->LDS, 16B/lane
            async16(a0 + (size_t)r * CIN + ko, &As[tid * 8]);
            async16(a1 + (size_t)r * CIN + ko, &As[2048 + tid * 8]);
            async16(bp + (size_t)r * CIN + ko, &Bs[tid * 8]);
            async16(bp + (size_t)(r + 64) * CIN + ko, &Bs[2048 + tid * 8]);
            __syncthreads();

            short8 af[4], bf[4];
#pragma unroll
            for (int i = 0; i < 4; ++i)
                af[i] = *(const short8*)&As[(rA + i * 16) * 32 + ks];
#pragma unroll
            for (int j = 0; j < 4; ++j)
                bf[j] = *(const short8*)&Bs[(rB + j * 16) * 32 + ks];
#pragma unroll
            for (int i = 0; i < 4; ++i)
#pragma unroll
                for (int j = 0; j < 4; ++j)
                    acc[i][j] = __builtin_amdgcn_mfma_f32_16x16x32_bf16(
                        af[i], bf[j], acc[i][j], 0, 0, 0);
            __syncthreads();
        }
    }

    // Epilogue: out[b,o,y,x] = acc * dinv[b,o] + bias[o]
    // C/D layout: n(col) = lane&15, m(row) = (lane>>4)*4 + reg
    int mbase = m0 + wm + (lane >> 4) * 4;
    int obase = n0 + wn + (lane & 15);
#pragma unroll
    for (int j = 0; j < 4; ++j) {
        int o = obase + j * 16;
        float dv = dinv[b * COUT + o];
        float bv = bias[o];
#pragma unroll
        for (int i = 0; i < 4; ++i) {
            int mm = mbase + i * 16;
            int y = (mm >> 6) & 63, xx = mm & 63;
            f32x4 v = acc[i][j] * dv + bv;
            *(f32x4*)(out + (((size_t)(b * COUT + o) * HH + y) * WW + xx)) = v;
        }
    }
}

// ---------------------------------------------------------------------------
extern "C" void kernel_launch(void* const* d_in, const int* in_sizes, int n_in,
                              void* d_out, int out_size, void* d_ws, size_t ws_size,
                              hipStream_t stream) {
    const float* x    = (const float*)d_in[0];  // [8,256,64,64]
    const float* s    = (const float*)d_in[1];  // [8,512]
    const float* w    = (const float*)d_in[2];  // [256,256,3,3]
    const float* bias = (const float*)d_in[3];  // [256,1,1]
    const float* aw   = (const float*)d_in[4];  // [256,512]
    const float* ab   = (const float*)d_in[5];  // [256]
    float* out = (float*)d_out;

    char* ws = (char*)d_ws;
    float* m            = (float*)(ws + 0);        //  8 KB  [8][256]
    float* wsq          = (float*)(ws + 8192);     // 256 KB [256][256]
    float* dinv         = (float*)(ws + 270336);   //  8 KB  [8][256]
    unsigned short* wb  = (unsigned short*)(ws + 278528);   // 1.18 MB [9][256][256]
    unsigned short* xpb = (unsigned short*)(ws + 1458176);  // 17.8 MB [8][66][66][256]

    k_style<<<BS, 256, 0, stream>>>(s, aw, ab, m);
    k_wprep<<<COUT, 256, 0, stream>>>(w, wb, wsq);
    k_dinv<<<BS, 256, 0, stream>>>(m, wsq, dinv);
    k_xprep<<<BS * HP, 256, 0, stream>>>(x, m, xpb);
    k_conv<<<512, 256, 0, stream>>>(xpb, wb, dinv, bias, out);
}

// Round 2
// 176.105 us; speedup vs baseline: 1.0225x; 1.0225x over previous
//
#include <hip/hip_runtime.h>
#include <hip/hip_bf16.h>
#include <stdint.h>

// Problem constants
#define BS   8
#define CIN  256
#define COUT 256
#define SD   512
#define HH   64
#define WW   64
#define HP   66   // padded spatial dim

typedef __attribute__((ext_vector_type(8))) short short8;
typedef __attribute__((ext_vector_type(4))) float f32x4;

__device__ __forceinline__ unsigned short f2bf(float f) {
    __hip_bfloat16 h = __float2bfloat16(f);
    return *reinterpret_cast<unsigned short*>(&h);
}

typedef __attribute__((address_space(3))) unsigned int lds_u32_t;
typedef const __attribute__((address_space(1))) unsigned int glb_u32_t;

__device__ __forceinline__ void async16(const void* g, void* l) {
    __builtin_amdgcn_global_load_lds((glb_u32_t*)g, (lds_u32_t*)l, 16, 0, 0);
}

// ---------------------------------------------------------------------------
// K1: repack w -> wb[t][o][i] (bf16 bits), and wsq[o][i] = sum_t w^2
// grid: COUT blocks x CIN threads
__global__ void k_wprep(const float* __restrict__ w, unsigned short* __restrict__ wb,
                        float* __restrict__ wsq) {
    int o = blockIdx.x, i = threadIdx.x;
    const float* wp = w + ((size_t)o * CIN + i) * 9;
    float v[9];
    float q = 0.f;
#pragma unroll
    for (int t = 0; t < 9; ++t) { v[t] = wp[t]; q += v[t] * v[t]; }
    wsq[o * CIN + i] = q;
#pragma unroll
    for (int t = 0; t < 9; ++t)
        wb[((size_t)t * COUT + o) * CIN + i] = f2bf(v[t]);
}

// ---------------------------------------------------------------------------
// K2: fused style GEMV + demod scale.
// block b: m[b,i] = s[b,:].aw[i,:] + ab[i] + 1 ; dinv[b,o] = rsqrt(sum m^2 wsq)
// Requires wsq from k_wprep (earlier launch, same stream).
__global__ void k_style_dinv(const float* __restrict__ s, const float* __restrict__ aw,
                             const float* __restrict__ ab, const float* __restrict__ wsq,
                             float* __restrict__ m, float* __restrict__ dinv) {
    int b = blockIdx.x;
    int i = threadIdx.x;
    __shared__ float sv[SD];
    __shared__ float m2[CIN];
    for (int d = i; d < SD; d += 256) sv[d] = s[b * SD + d];
    __syncthreads();
    const float4* awr = (const float4*)(aw + (size_t)i * SD);
    float acc = 0.f;
#pragma unroll 4
    for (int d4 = 0; d4 < SD / 4; ++d4) {
        float4 w4 = awr[d4];
        acc += w4.x * sv[d4 * 4] + w4.y * sv[d4 * 4 + 1] +
               w4.z * sv[d4 * 4 + 2] + w4.w * sv[d4 * 4 + 3];
    }
    float mv = acc + ab[i] + 1.0f;
    m[b * CIN + i] = mv;
    m2[i] = mv * mv;
    __syncthreads();
    const float4* wq = (const float4*)(wsq + (size_t)i * CIN);
    float a2 = 0.f;
#pragma unroll 4
    for (int i4 = 0; i4 < CIN / 4; ++i4) {
        float4 q = wq[i4];
        a2 += q.x * m2[i4 * 4] + q.y * m2[i4 * 4 + 1] +
              q.z * m2[i4 * 4 + 2] + q.w * m2[i4 * 4 + 3];
    }
    dinv[b * COUT + i] = rsqrtf(a2 + 1e-8f);
}

// ---------------------------------------------------------------------------
// K3: x' = x * m, NCHW fp32 -> zero-padded NHWC bf16 [BS][66][66][CIN].
// Register transpose, no LDS: thread owns (8ch x 4x) micro-tile.
// Loads: 8 x float4, lanes 0-15 cover 256B contiguous per channel row.
// Stores: dwordx4; lanes {l,l+16,l+32,l+48} complete full 64B lines.
// grid: BS*HP blocks x 256 threads
__global__ void k_xprep(const float* __restrict__ x, const float* __restrict__ m,
                        unsigned short* __restrict__ xp) {
    int bi = blockIdx.x;
    int b = bi / HP, yp = bi % HP;
    unsigned short* row = xp + ((size_t)(b * HP + yp)) * HP * CIN;
    int tid = threadIdx.x;

    if (yp == 0 || yp == HP - 1) {
        uint4 z = {0u, 0u, 0u, 0u};
        uint4* r = (uint4*)row;                // HP*CIN*2 / 16 = 2112 chunks
        for (int j = tid; j < HP * CIN / 8; j += 256) r[j] = z;
        return;
    }
    int y = yp - 1;

    // zero border columns xp=0 and xp=65 (each 512B = 32 uint4)
    if (tid < 64) {
        uint4 z = {0u, 0u, 0u, 0u};
        if (tid < 32) ((uint4*)row)[tid] = z;
        else ((uint4*)(row + (size_t)(HP - 1) * CIN))[tid - 32] = z;
    }

#pragma unroll
    for (int it = 0; it < 2; ++it) {
        int u = it * 256 + tid;
        int x0 = (u & 15) * 4;
        int i0 = (u >> 4) * 8;
        float vv[8][4];
        float mv[8];
#pragma unroll
        for (int k = 0; k < 8; ++k) {
            *(float4*)vv[k] = *(const float4*)&x[(((size_t)b * CIN + i0 + k) * HH + y) * WW + x0];
            mv[k] = m[b * CIN + i0 + k];
        }
#pragma unroll
        for (int j = 0; j < 4; ++j) {
            short8 p;
#pragma unroll
            for (int k = 0; k < 8; ++k)
                p[k] = (short)f2bf(vv[k][j] * mv[k]);
            *(short8*)&row[(size_t)(x0 + j + 1) * CIN + i0] = p;
        }
    }
}

// ---------------------------------------------------------------------------
// K4: implicit GEMM conv. M = BS*HH*WW, N = COUT, K = 9 taps x 256 ch.
// 128x128 tile, BK=64 (4 kc chunks), A-region (4 rows x 66 cols x 64 ch)
// resident in LDS across all 9 taps of a kc. XOR chunk swizzle (applied to
// the staging SOURCE address, so global_load_lds's lane-contiguous LDS
// destination is preserved) kills ds_read_b128 bank conflicts.
// Epilogue: *dinv[b,o] + bias[o], f32x4 stores to NCHW (full 64B lines).
__global__ void k_conv(const unsigned short* __restrict__ xp,
                       const unsigned short* __restrict__ wb,
                       const float* __restrict__ dinv,
                       const float* __restrict__ bias,
                       float* __restrict__ out) {
    __shared__ unsigned short Ar[2112 * 8];   // 33792 B: [4 rows][66 cols][8 chunks x 16B]
    __shared__ unsigned short Bs[1024 * 8];   // 16384 B: [128 rows][8 chunks x 16B]

    int bx = blockIdx.x;
    int mt = bx & 255;          // M-tile; bx and bx+256 share it -> same XCD (256%8==0)
    int n0 = (bx >> 8) << 7;    // N-tile (0 or 128)
    int m0 = mt << 7;
    int b  = m0 >> 12;
    int y0 = (m0 >> 6) & 63;    // padded row base of the 4-row A-region

    int tid = threadIdx.x;
    int lane = tid & 63, wid = tid >> 6;
    int wm = (wid & 1) << 6, wn = (wid >> 1) << 6;
    int quad = lane >> 4;
    int mrow = lane & 15;
    int yr = wm >> 6;           // image row within tile handled by this wave (0/1)

    f32x4 acc[4][4] = {};

    const unsigned short* xb = xp + (size_t)b * HP * HP * CIN;

#pragma unroll 1
    for (int kc = 0; kc < 4; ++kc) {
        int ch0 = kc * 64;
        // ---- stage A-region: 2112 chunks of 16B (8 full calls + 1 wave-0 call)
#pragma unroll
        for (int k = 0; k < 8; ++k) {
            int sA = k * 256 + tid;
            int rowA = sA / 528;
            int rem = sA - rowA * 528;
            int colA = rem >> 3, c4 = rem & 7;
            async16(xb + ((size_t)(y0 + rowA) * HP + colA) * CIN + ch0 + ((c4 ^ (colA & 7)) << 3),
                    &Ar[(size_t)sA * 8]);
        }
        if (tid < 64) {   // tail = exactly wave 0, no intra-wave divergence
            int sA = 2048 + tid;
            int rowA = sA / 528;
            int rem = sA - rowA * 528;
            int colA = rem >> 3, c4 = rem & 7;
            async16(xb + ((size_t)(y0 + rowA) * HP + colA) * CIN + ch0 + ((c4 ^ (colA & 7)) << 3),
                    &Ar[(size_t)sA * 8]);
        }

#pragma unroll 1
        for (int t = 0; t < 9; ++t) {
            int dy = t / 3, dx = t % 3;
            // ---- stage B: 128 rows x 64 ch = 1024 chunks
            const unsigned short* bp = wb + ((size_t)t * COUT + n0) * CIN + ch0;
#pragma unroll
            for (int k = 0; k < 4; ++k) {
                int sB = k * 256 + tid;
                int rowB = sB >> 3, c4 = sB & 7;
                async16(bp + (size_t)rowB * CIN + ((c4 ^ (rowB & 7)) << 3),
                        &Bs[(size_t)sB * 8]);
            }
            __syncthreads();

            int arow = yr + dy;
#pragma unroll
            for (int h = 0; h < 2; ++h) {
                short8 af[4], bf[4];
#pragma unroll
                for (int i = 0; i < 4; ++i) {
                    int xd = mrow + i * 16 + dx;
                    int chunk = arow * 528 + xd * 8 + ((h * 4 + quad) ^ (xd & 7));
                    af[i] = *(const short8*)&Ar[chunk * 8];
                }
#pragma unroll
                for (int j = 0; j < 4; ++j) {
                    int rowB = wn + mrow + j * 16;
                    int chunk = rowB * 8 + ((h * 4 + quad) ^ (rowB & 7));
                    bf[j] = *(const short8*)&Bs[chunk * 8];
                }
#pragma unroll
                for (int i = 0; i < 4; ++i)
#pragma unroll
                    for (int j = 0; j < 4; ++j)
                        acc[i][j] = __builtin_amdgcn_mfma_f32_16x16x32_bf16(
                            af[i], bf[j], acc[i][j], 0, 0, 0);
            }
            __syncthreads();
        }
    }

    // Epilogue: out[b,o,y,x] = acc * dinv[b,o] + bias[o]
    // C/D layout: n(col) = lane&15, m(row) = quad*4 + reg
    int mbase = m0 + wm + quad * 4;
    int obase = n0 + wn + mrow;
#pragma unroll
    for (int j = 0; j < 4; ++j) {
        int o = obase + j * 16;
        float dv = dinv[b * COUT + o];
        float bv = bias[o];
#pragma unroll
        for (int i = 0; i < 4; ++i) {
            int mm = mbase + i * 16;
            int y = (mm >> 6) & 63, xx = mm & 63;
            f32x4 v = acc[i][j] * dv + bv;
            *(f32x4*)(out + (((size_t)(b * COUT + o) * HH + y) * WW + xx)) = v;
        }
    }
}

// ---------------------------------------------------------------------------
extern "C" void kernel_launch(void* const* d_in, const int* in_sizes, int n_in,
                              void* d_out, int out_size, void* d_ws, size_t ws_size,
                              hipStream_t stream) {
    const float* x    = (const float*)d_in[0];  // [8,256,64,64]
    const float* s    = (const float*)d_in[1];  // [8,512]
    const float* w    = (const float*)d_in[2];  // [256,256,3,3]
    const float* bias = (const float*)d_in[3];  // [256,1,1]
    const float* aw   = (const float*)d_in[4];  // [256,512]
    const float* ab   = (const float*)d_in[5];  // [256]
    float* out = (float*)d_out;

    char* ws = (char*)d_ws;
    float* m            = (float*)(ws + 0);        //  8 KB  [8][256]
    float* wsq          = (float*)(ws + 8192);     // 256 KB [256][256]
    float* dinv         = (float*)(ws + 270336);   //  8 KB  [8][256]
    unsigned short* wb  = (unsigned short*)(ws + 278528);   // 1.18 MB [9][256][256]
    unsigned short* xpb = (unsigned short*)(ws + 1458176);  // 17.8 MB [8][66][66][256]

    k_wprep<<<COUT, 256, 0, stream>>>(w, wb, wsq);
    k_style_dinv<<<BS, 256, 0, stream>>>(s, aw, ab, wsq, m, dinv);
    k_xprep<<<BS * HP, 256, 0, stream>>>(x, m, xpb);
    k_conv<<<512, 256, 0, stream>>>(xpb, wb, dinv, bias, out);
}

// Round 3
// 137.697 us; speedup vs baseline: 1.3078x; 1.2789x over previous
//
#include <hip/hip_runtime.h>
#include <hip/hip_bf16.h>
#include <stdint.h>

// Problem constants
#define BS   8
#define CIN  256
#define COUT 256
#define SD   512
#define HH   64
#define WW   64
#define HP   66   // padded spatial dim

typedef __attribute__((ext_vector_type(8))) short short8;
typedef __attribute__((ext_vector_type(4))) float f32x4;

__device__ __forceinline__ unsigned short f2bf(float f) {
    __hip_bfloat16 h = __float2bfloat16(f);
    return *reinterpret_cast<unsigned short*>(&h);
}

typedef __attribute__((address_space(3))) unsigned int lds_u32_t;
typedef const __attribute__((address_space(1))) unsigned int glb_u32_t;

__device__ __forceinline__ void async16(const void* g, void* l) {
    __builtin_amdgcn_global_load_lds((glb_u32_t*)g, (lds_u32_t*)l, 16, 0, 0);
}

// ---------------------------------------------------------------------------
// K1: m[b,i] = s[b,:].aw[i,:] + ab[i] + 1
// grid 64 blocks: bx = b*8 + chunk(32 rows). 256 thr = 32 rows x 8 parts.
// Each thread: 64-MAC partial dot; 3-step shuffle reduce over parts.
__global__ void k_style(const float* __restrict__ s, const float* __restrict__ aw,
                        const float* __restrict__ ab, float* __restrict__ m) {
    int b = blockIdx.x >> 3, chunk = blockIdx.x & 7;
    int tid = threadIdx.x;
    __shared__ float sv[SD];
    for (int d = tid; d < SD; d += 256) sv[d] = s[b * SD + d];
    __syncthreads();
    int il = tid >> 3, p = tid & 7;
    int i = chunk * 32 + il;
    const float4* awr = (const float4*)(aw + (size_t)i * SD + p * 64);
    float acc = 0.f;
#pragma unroll
    for (int d4 = 0; d4 < 16; ++d4) {
        float4 w4 = awr[d4];
        int d0 = p * 64 + d4 * 4;
        acc += w4.x * sv[d0] + w4.y * sv[d0 + 1] + w4.z * sv[d0 + 2] + w4.w * sv[d0 + 3];
    }
    acc += __shfl_xor(acc, 1);
    acc += __shfl_xor(acc, 2);
    acc += __shfl_xor(acc, 4);
    if (p == 0) m[b * CIN + i] = acc + ab[i] + 1.0f;
}

// ---------------------------------------------------------------------------
// K2: repack w -> wb[t][o][i] (bf16), and dinv[b,o] = rsqrt(sum_i m2*wsq + 1e-8)
// fused (wsq never hits global). grid: COUT blocks x CIN threads.
__global__ void k_wprep_dinv(const float* __restrict__ w, const float* __restrict__ m,
                             unsigned short* __restrict__ wb, float* __restrict__ dinv) {
    int o = blockIdx.x, i = threadIdx.x;
    const float* wp = w + ((size_t)o * CIN + i) * 9;
    float v[9];
    float q = 0.f;
#pragma unroll
    for (int t = 0; t < 9; ++t) { v[t] = wp[t]; q += v[t] * v[t]; }
#pragma unroll
    for (int t = 0; t < 9; ++t)
        wb[((size_t)t * COUT + o) * CIN + i] = f2bf(v[t]);

    float r[8];
#pragma unroll
    for (int b = 0; b < 8; ++b) {
        float mv = m[b * CIN + i];
        r[b] = q * mv * mv;
    }
#pragma unroll
    for (int b = 0; b < 8; ++b) {
        r[b] += __shfl_xor(r[b], 1);
        r[b] += __shfl_xor(r[b], 2);
        r[b] += __shfl_xor(r[b], 4);
        r[b] += __shfl_xor(r[b], 8);
        r[b] += __shfl_xor(r[b], 16);
        r[b] += __shfl_xor(r[b], 32);
    }
    __shared__ float red[4][8];
    int lane = i & 63, wid = i >> 6;
    if (lane == 0) {
#pragma unroll
        for (int b = 0; b < 8; ++b) red[wid][b] = r[b];
    }
    __syncthreads();
    if (i < 8) {
        float acc = red[0][i] + red[1][i] + red[2][i] + red[3][i];
        dinv[i * COUT + o] = rsqrtf(acc + 1e-8f);
    }
}

// ---------------------------------------------------------------------------
// K3: x' = x * m, NCHW fp32 -> zero-padded NHWC bf16 [BS][66][66][CIN].
// Register transpose, no LDS. grid: BS*HP blocks x 256 threads.
__global__ void k_xprep(const float* __restrict__ x, const float* __restrict__ m,
                        unsigned short* __restrict__ xp) {
    int bi = blockIdx.x;
    int b = bi / HP, yp = bi % HP;
    unsigned short* row = xp + ((size_t)(b * HP + yp)) * HP * CIN;
    int tid = threadIdx.x;

    if (yp == 0 || yp == HP - 1) {
        uint4 z = {0u, 0u, 0u, 0u};
        uint4* r = (uint4*)row;
        for (int j = tid; j < HP * CIN / 8; j += 256) r[j] = z;
        return;
    }
    int y = yp - 1;

    if (tid < 64) {
        uint4 z = {0u, 0u, 0u, 0u};
        if (tid < 32) ((uint4*)row)[tid] = z;
        else ((uint4*)(row + (size_t)(HP - 1) * CIN))[tid - 32] = z;
    }

#pragma unroll
    for (int it = 0; it < 2; ++it) {
        int u = it * 256 + tid;
        int x0 = (u & 15) * 4;
        int i0 = (u >> 4) * 8;
        float vv[8][4];
        float mv[8];
#pragma unroll
        for (int k = 0; k < 8; ++k) {
            *(float4*)vv[k] = *(const float4*)&x[(((size_t)b * CIN + i0 + k) * HH + y) * WW + x0];
            mv[k] = m[b * CIN + i0 + k];
        }
#pragma unroll
        for (int j = 0; j < 4; ++j) {
            short8 p;
#pragma unroll
            for (int k = 0; k < 8; ++k)
                p[k] = (short)f2bf(vv[k][j] * mv[k]);
            *(short8*)&row[(size_t)(x0 + j + 1) * CIN + i0] = p;
        }
    }
}

// ---------------------------------------------------------------------------
// K4: implicit GEMM conv, software-pipelined.
// Tile 128x128. 4 waves = (2 m-halves) x (2 k-halves); each wave 64m x 128n
// over 32 channels -> per-tap per-wave LDS reads 12KB (vs 16KB at 64x64).
// B double-buffered: prefetch tap g+1 before computing tap g, one barrier
// per tap; the compiler's vmcnt(0)-before-barrier then drains AFTER compute.
// A-region (4 rows x 66 x 64ch) staged once per kc, reused by all 9 taps.
// XOR chunk swizzle on staging source keeps ds_read_b128 conflict-free.
// Epilogue: cross-wave k-half reduction via LDS scratch, *dinv + bias.
__global__ void __launch_bounds__(256, 2)
k_conv(const unsigned short* __restrict__ xp,
       const unsigned short* __restrict__ wb,
       const float* __restrict__ dinv,
       const float* __restrict__ bias,
       float* __restrict__ out) {
    __shared__ unsigned short smem[33280];      // 66560 B
    unsigned short* Ar = smem;                  // 16896 shorts = 33792 B
    unsigned short* Bs = smem + 16896;          // 2 bufs x 8192 shorts = 32768 B

    int bx = blockIdx.x;
    int mt = bx & 255;          // bx and bx+256 share the M-tile -> same XCD
    int n0 = (bx >> 8) << 7;
    int m0 = mt << 7;
    int b  = m0 >> 12;
    int y0 = (m0 >> 6) & 63;

    int tid = threadIdx.x;
    int lane = tid & 63, wid = tid >> 6;
    int mhalf = wid & 1, khalf = wid >> 1;
    int quad = lane >> 4, mrow = lane & 15;
    int hq = khalf * 4 + quad;   // k-chunk index within 8 (16B chunks of 64 ch)

    f32x4 acc[4][8] = {};

    const unsigned short* xb = xp + (size_t)b * HP * HP * CIN;

    auto stageB = [&](int tt, int cc, int buf) {
        const unsigned short* bp = wb + ((size_t)tt * COUT + n0) * CIN + cc * 64;
        unsigned short* dst = Bs + buf * 8192;
#pragma unroll
        for (int k = 0; k < 4; ++k) {
            int sB = k * 256 + tid;
            int rowB = sB >> 3, c4 = sB & 7;
            async16(bp + (size_t)rowB * CIN + ((c4 ^ (rowB & 7)) << 3), dst + sB * 8);
        }
    };

    stageB(0, 0, 0);
    int bufc = 0;
    int tn = 1, cn = 0;   // next (tap, chunk) to prefetch

#pragma unroll 1
    for (int kc = 0; kc < 4; ++kc) {
        int ch0 = kc * 64;
        // ---- stage A-region: 2112 chunks of 16B
#pragma unroll
        for (int k = 0; k < 8; ++k) {
            int sA = k * 256 + tid;
            int rowA = sA / 528;
            int rem = sA - rowA * 528;
            int colA = rem >> 3, c4 = rem & 7;
            async16(xb + ((size_t)(y0 + rowA) * HP + colA) * CIN + ch0 + ((c4 ^ (colA & 7)) << 3),
                    &Ar[(size_t)sA * 8]);
        }
        if (tid < 64) {
            int sA = 2048 + tid;
            int rowA = sA / 528;
            int rem = sA - rowA * 528;
            int colA = rem >> 3, c4 = rem & 7;
            async16(xb + ((size_t)(y0 + rowA) * HP + colA) * CIN + ch0 + ((c4 ^ (colA & 7)) << 3),
                    &Ar[(size_t)sA * 8]);
        }
        __syncthreads();   // drains A stage + pending B prefetch

#pragma unroll 1
        for (int t = 0; t < 9; ++t) {
            int g = kc * 9 + t;
            if (g < 35) stageB(tn, cn, bufc ^ 1);   // prefetch BEFORE compute

            int dy = t / 3, dx = t - dy * 3;
            int arow = mhalf + dy;
            const unsigned short* Bcur = Bs + bufc * 8192;

            short8 af[4], bf[8];
#pragma unroll
            for (int i = 0; i < 4; ++i) {
                int xd = mrow + i * 16 + dx;
                int chunk = arow * 528 + xd * 8 + (hq ^ (xd & 7));
                af[i] = *(const short8*)&Ar[chunk * 8];
            }
#pragma unroll
            for (int j = 0; j < 8; ++j) {
                int rowB = mrow + j * 16;
                int chunk = rowB * 8 + (hq ^ (rowB & 7));
                bf[j] = *(const short8*)&Bcur[chunk * 8];
            }
#pragma unroll
            for (int i = 0; i < 4; ++i)
#pragma unroll
                for (int j = 0; j < 8; ++j)
                    acc[i][j] = __builtin_amdgcn_mfma_f32_16x16x32_bf16(
                        af[i], bf[j], acc[i][j], 0, 0, 0);

            __syncthreads();  // vmcnt(0) drain lands after compute: prefetch hidden
            bufc ^= 1;
            if (++tn == 9) { tn = 0; ++cn; }
        }
    }

    // ---- Epilogue: reduce k-halves via LDS scratch, then *dinv + bias, store.
    // C/D layout: n(col) = mrow, m(row) = quad*4 + reg.
    f32x4* scr = (f32x4*)smem;       // [2 mhalf][64 lane][17 (16+pad)] = 34816 B
    int mbase = m0 + mhalf * 64 + quad * 4;
#pragma unroll
    for (int p = 0; p < 2; ++p) {
        __syncthreads();
        if (khalf == 1) {
#pragma unroll
            for (int i = 0; i < 4; ++i)
#pragma unroll
                for (int j2 = 0; j2 < 4; ++j2)
                    scr[(mhalf * 64 + lane) * 17 + i * 4 + j2] = acc[i][p * 4 + j2];
        }
        __syncthreads();
        if (khalf == 0) {
#pragma unroll
            for (int j2 = 0; j2 < 4; ++j2) {
                int j = p * 4 + j2;
                int o = n0 + j * 16 + mrow;
                float dv = dinv[b * COUT + o];
                float bv = bias[o];
#pragma unroll
                for (int i = 0; i < 4; ++i) {
                    f32x4 v = acc[i][j] + scr[(mhalf * 64 + lane) * 17 + i * 4 + j2];
                    v = v * dv + bv;
                    int mm = mbase + i * 16;
                    int y = (mm >> 6) & 63, xx = mm & 63;
                    *(f32x4*)(out + (((size_t)(b * COUT + o) * HH + y) * WW + xx)) = v;
                }
            }
        }
    }
}

// ---------------------------------------------------------------------------
extern "C" void kernel_launch(void* const* d_in, const int* in_sizes, int n_in,
                              void* d_out, int out_size, void* d_ws, size_t ws_size,
                              hipStream_t stream) {
    const float* x    = (const float*)d_in[0];  // [8,256,64,64]
    const float* s    = (const float*)d_in[1];  // [8,512]
    const float* w    = (const float*)d_in[2];  // [256,256,3,3]
    const float* bias = (const float*)d_in[3];  // [256,1,1]
    const float* aw   = (const float*)d_in[4];  // [256,512]
    const float* ab   = (const float*)d_in[5];  // [256]
    float* out = (float*)d_out;

    char* ws = (char*)d_ws;
    float* m            = (float*)(ws + 0);                 //  8 KB [8][256]
    float* dinv         = (float*)(ws + 8192);              //  8 KB [8][256]
    unsigned short* wb  = (unsigned short*)(ws + 16384);    // 1.18 MB [9][256][256]
    unsigned short* xpb = (unsigned short*)(ws + 1196032);  // 17.8 MB [8][66][66][256]

    k_style<<<64, 256, 0, stream>>>(s, aw, ab, m);
    k_wprep_dinv<<<COUT, 256, 0, stream>>>(w, m, wb, dinv);
    k_xprep<<<BS * HP, 256, 0, stream>>>(x, m, xpb);
    k_conv<<<512, 256, 0, stream>>>(xpb, wb, dinv, bias, out);
}